// Round 1
// baseline (78.829 us; speedup 1.0000x reference)
//
#include <hip/hip_runtime.h>
#include <math.h>

// Problem: x[N=16,T=128,V=64,F=16] fp32, a[F=16] fp32.
// score[n,i,j] = (1/T) * sum_t sum_f a[f]*|x[n,t,i,f]-x[n,t,j,f]|
// e = exp(relu(score)); out[n,i,j] = e[n,i,j] / sum_i e[n,i,j]   (column norm)
//
// FUSED single kernel, zero workspace:
//  - column-norm sums over i, which lives in a wave's 64 lanes -> a block that
//    owns (n, 4 j's, full T) needs no cross-block reduction and no d_ws.
//  - grid (16 n, 16 z) = 256 blocks (1/CU), 4 waves; wave w = T-quarter (32 t).
//  - No LDS staging: A-rows read per-lane from global (4x dwordx4 over a
//    contiguous 4KB window per t -> cache-line friendly, re-reads L2-served,
//    same-n blocks co-locate on one XCD since block ids differ by 16).
//    B-rows are wave-uniform -> broadcast loads of already-warm lines.
//  - Epilogue: 4KB LDS combine over T-quarters + 64-lane shuffle-sum for the
//    column normalizer.

#define Nn 16
#define Tt 128
#define Vv 64
#define Ff 16
#define TSPLIT 4
#define TPW (Tt / TSPLIT)   // 32 t's per wave
#define JPB 4               // j's per block (each wave computes all 4)

__global__ __launch_bounds__(256) void gls_fused(const float* __restrict__ x,
                                                 const float* __restrict__ a,
                                                 float* __restrict__ out) {
    const int n   = blockIdx.x;
    const int z   = blockIdx.y;
    const int j0  = z * JPB;
    const int tid = threadIdx.x;
    const int i   = tid & 63;
    const int w   = __builtin_amdgcn_readfirstlane(tid >> 6);

    float af[Ff];
#pragma unroll
    for (int f = 0; f < Ff; ++f) af[f] = a[f];   // uniform -> SGPRs

    float acc[JPB] = {0.f, 0.f, 0.f, 0.f};

    // base of this wave's T-quarter, in float4 units (V*F/4 = 256 float4 per t)
    const float4* xb = (const float4*)x + (size_t)(n * Tt + w * TPW) * (Vv * Ff / 4);

#pragma unroll 2
    for (int t = 0; t < TPW; ++t) {
        const float4* xt = xb + (size_t)t * (Vv * Ff / 4);
        // A-row for lane i: 4 x dwordx4, lane-stride 64B -> contiguous 4KB/wave
        const float4 A0 = xt[i * 4 + 0];
        const float4 A1 = xt[i * 4 + 1];
        const float4 A2 = xt[i * 4 + 2];
        const float4 A3 = xt[i * 4 + 3];
#pragma unroll
        for (int jj = 0; jj < JPB; ++jj) {
            const float4* xj = xt + (j0 + jj) * 4;   // wave-uniform -> broadcast
            const float4 B0 = xj[0];
            const float4 B1 = xj[1];
            const float4 B2 = xj[2];
            const float4 B3 = xj[3];
            float s = acc[jj];
            s = fmaf(fabsf(A0.x - B0.x), af[0],  s);
            s = fmaf(fabsf(A0.y - B0.y), af[1],  s);
            s = fmaf(fabsf(A0.z - B0.z), af[2],  s);
            s = fmaf(fabsf(A0.w - B0.w), af[3],  s);
            s = fmaf(fabsf(A1.x - B1.x), af[4],  s);
            s = fmaf(fabsf(A1.y - B1.y), af[5],  s);
            s = fmaf(fabsf(A1.z - B1.z), af[6],  s);
            s = fmaf(fabsf(A1.w - B1.w), af[7],  s);
            s = fmaf(fabsf(A2.x - B2.x), af[8],  s);
            s = fmaf(fabsf(A2.y - B2.y), af[9],  s);
            s = fmaf(fabsf(A2.z - B2.z), af[10], s);
            s = fmaf(fabsf(A2.w - B2.w), af[11], s);
            s = fmaf(fabsf(A3.x - B3.x), af[12], s);
            s = fmaf(fabsf(A3.y - B3.y), af[13], s);
            s = fmaf(fabsf(A3.z - B3.z), af[14], s);
            s = fmaf(fabsf(A3.w - B3.w), af[15], s);
            acc[jj] = s;
        }
    }

    // ---- combine T-quarters across the 4 waves (4 KB LDS) ----
    __shared__ float part[TSPLIT][JPB][Vv];
#pragma unroll
    for (int jj = 0; jj < JPB; ++jj)
        part[w][jj][i] = acc[jj];
    __syncthreads();

    // wave w finalizes column j = j0 + w; lane = row index i
    float s = part[0][w][i] + part[1][w][i] + part[2][w][i] + part[3][w][i];
    const float e = expf(fmaxf(s * (1.0f / (float)Tt), 0.0f));
    float tsum = e;
#pragma unroll
    for (int m = 1; m < 64; m <<= 1) tsum += __shfl_xor(tsum, m, 64);

    out[((size_t)n * Vv + i) * Vv + (j0 + w)] = e / tsum;   // tiny scatter (256 KB total)
}

extern "C" void kernel_launch(void* const* d_in, const int* in_sizes, int n_in,
                              void* d_out, int out_size, void* d_ws, size_t ws_size,
                              hipStream_t stream) {
    const float* x = (const float*)d_in[0];   // [16,128,64,16]
    const float* a = (const float*)d_in[1];   // [16,1]
    float* out = (float*)d_out;               // [16,64,64]
    (void)d_ws; (void)ws_size;                // workspace intentionally unused

    dim3 g(Nn, Vv / JPB);                     // (16, 16)
    gls_fused<<<g, 256, 0, stream>>>(x, a, out);
}

// Round 2
// 67.292 us; speedup vs baseline: 1.1714x; 1.1714x over previous
//
#include <hip/hip_runtime.h>
#include <math.h>

// Problem: x[N=16,T=128,V=64,F=16] fp32, a[F=16] fp32.
// score[n,i,j] = (1/T) * sum_t sum_f a[f]*|x[n,t,i,f]-x[n,t,j,f]|
// e = exp(relu(score)); out[n,i,j] = e[n,i,j] / sum_i e[n,i,j]   (column norm)
//
// FUSED single kernel, zero workspace. Round-2 fix: round-1 ran 256-thread
// blocks = 1 wave/SIMD -> latency-exposed global loads (regressed to 78.8us).
// Now: 1024-thread blocks (16 waves = 4 waves/SIMD), each wave owns T/16 = 8
// timesteps for the block's (n, 4 j's). Same total VALU work (~3.4us floor),
// 4x the latency hiding. Column-norm still block-local: i lives in the 64
// lanes, T-partials combine through 16KB LDS.
//  - A-rows: per-lane dwordx4 x4, wave covers a contiguous 4KB/t (L2-served;
//    same-n blocks land on one XCD since grid ids differ by 16 -> ~1MB/XCD).
//  - B-rows: wave-uniform address -> scalar/broadcast loads of warm lines.

#define Nn 16
#define Tt 128
#define Vv 64
#define Ff 16
#define WAVES 16
#define TPW (Tt / WAVES)    // 8 t's per wave
#define JPB 4               // j's per block

__global__ __launch_bounds__(1024, 4) void gls_fused(const float* __restrict__ x,
                                                     const float* __restrict__ a,
                                                     float* __restrict__ out) {
    const int n   = blockIdx.x;
    const int z   = blockIdx.y;
    const int j0  = z * JPB;
    const int tid = threadIdx.x;
    const int i   = tid & 63;
    const int w   = __builtin_amdgcn_readfirstlane(tid >> 6);

    float af[Ff];
#pragma unroll
    for (int f = 0; f < Ff; ++f) af[f] = a[f];   // uniform -> SGPRs

    float acc[JPB] = {0.f, 0.f, 0.f, 0.f};

    // base of this wave's T-slice, in float4 units (V*F/4 = 256 float4 per t)
    const float4* xb = (const float4*)x + (size_t)(n * Tt + w * TPW) * (Vv * Ff / 4);

#pragma unroll 2
    for (int t = 0; t < TPW; ++t) {
        const float4* xt = xb + (size_t)t * (Vv * Ff / 4);
        // A-row for lane i: 4 x dwordx4, 64B/lane -> contiguous 4KB per wave
        const float4 A0 = xt[i * 4 + 0];
        const float4 A1 = xt[i * 4 + 1];
        const float4 A2 = xt[i * 4 + 2];
        const float4 A3 = xt[i * 4 + 3];
#pragma unroll
        for (int jj = 0; jj < JPB; ++jj) {
            const float4* xj = xt + (j0 + jj) * 4;   // wave-uniform -> broadcast
            const float4 B0 = xj[0];
            const float4 B1 = xj[1];
            const float4 B2 = xj[2];
            const float4 B3 = xj[3];
            float s = acc[jj];
            s = fmaf(fabsf(A0.x - B0.x), af[0],  s);
            s = fmaf(fabsf(A0.y - B0.y), af[1],  s);
            s = fmaf(fabsf(A0.z - B0.z), af[2],  s);
            s = fmaf(fabsf(A0.w - B0.w), af[3],  s);
            s = fmaf(fabsf(A1.x - B1.x), af[4],  s);
            s = fmaf(fabsf(A1.y - B1.y), af[5],  s);
            s = fmaf(fabsf(A1.z - B1.z), af[6],  s);
            s = fmaf(fabsf(A1.w - B1.w), af[7],  s);
            s = fmaf(fabsf(A2.x - B2.x), af[8],  s);
            s = fmaf(fabsf(A2.y - B2.y), af[9],  s);
            s = fmaf(fabsf(A2.z - B2.z), af[10], s);
            s = fmaf(fabsf(A2.w - B2.w), af[11], s);
            s = fmaf(fabsf(A3.x - B3.x), af[12], s);
            s = fmaf(fabsf(A3.y - B3.y), af[13], s);
            s = fmaf(fabsf(A3.z - B3.z), af[14], s);
            s = fmaf(fabsf(A3.w - B3.w), af[15], s);
            acc[jj] = s;
        }
    }

    // ---- combine the 16 T-slices (16 KB LDS) ----
    __shared__ float part[WAVES][JPB][Vv];
#pragma unroll
    for (int jj = 0; jj < JPB; ++jj)
        part[w][jj][i] = acc[jj];                 // lane-contiguous, conflict-free
    __syncthreads();

    if (w < JPB) {
        // wave w finalizes column j = j0 + w; lane = row index i
        float s = 0.f;
#pragma unroll
        for (int p = 0; p < WAVES; ++p)
            s += part[p][w][i];
        const float e = expf(fmaxf(s * (1.0f / (float)Tt), 0.0f));
        float tsum = e;
#pragma unroll
        for (int m = 1; m < 64; m <<= 1) tsum += __shfl_xor(tsum, m, 64);

        out[((size_t)n * Vv + i) * Vv + (j0 + w)] = e / tsum;  // tiny scatter (256 KB total)
    }
}

extern "C" void kernel_launch(void* const* d_in, const int* in_sizes, int n_in,
                              void* d_out, int out_size, void* d_ws, size_t ws_size,
                              hipStream_t stream) {
    const float* x = (const float*)d_in[0];   // [16,128,64,16]
    const float* a = (const float*)d_in[1];   // [16,1]
    float* out = (float*)d_out;               // [16,64,64]
    (void)d_ws; (void)ws_size;                // workspace intentionally unused

    dim3 g(Nn, Vv / JPB);                     // (16, 16) = 256 blocks, 1/CU
    gls_fused<<<g, 1024, 0, stream>>>(x, a, out);
}